// Round 4
// baseline (117.104 us; speedup 1.0000x reference)
//
#include <hip/hip_runtime.h>

// Fused persistent kernel — fully WAVE-LOCAL steps.
// 14-step recurrence, N=1680:
//   temp = J @ r_{t-1};  U = temp + Iext;  sq = (0.2U)^2
//   recSum = 0.005*sum(sq);  r_t = sq/recSum
// Invariant: carry unnormalized r̃_t = sq_t;  s_t = 0.005*sum(r̃_t);
//   J @ r_{t-1} = (J @ r̃_{t-1}) / s_{t-1}.
//
// Each wave owns 4 output rows. Lane l needs exactly quads l+64k (k=0..6)
// of r̃ — the wave's 64 lanes tile all 420 quads. So each step is entirely
// wave-local: poll own quads from LLC (batched 7x dwordx4 sc0|sc1, one
// vmcnt(0) per pass), derive s_{t-1} from the same data in the same
// butterfly as the row-dots, publish own sq quad. No LDS, no __syncthreads
// in the loop, no fences. Data IS the barrier: 14 per-step buffers
// sentinel-filled 0xBF (-1.498f < 0) per launch; valid iff all elems >= 0
// (sq is a square). J rows are pinned in VGPRs via a loop-carried asm tie.

typedef float f32x4 __attribute__((ext_vector_type(4)));

#define N      1680
#define NV4    420          // N/4
#define NSTEP  14
#define GBLK   105          // blocks; 105*16 = 1680 rows
#define RPB    16           // rows per block
#define RPW    4            // rows per wave

__device__ __forceinline__ void load7_llc(
    const f32x4* p0, const f32x4* p1, const f32x4* p2, const f32x4* p3,
    const f32x4* p4, const f32x4* p5, const f32x4* p6,
    f32x4& v0, f32x4& v1, f32x4& v2, f32x4& v3,
    f32x4& v4, f32x4& v5, f32x4& v6)
{
    asm volatile(
        "global_load_dwordx4 %0, %7, off sc0 sc1\n\t"
        "global_load_dwordx4 %1, %8, off sc0 sc1\n\t"
        "global_load_dwordx4 %2, %9, off sc0 sc1\n\t"
        "global_load_dwordx4 %3, %10, off sc0 sc1\n\t"
        "global_load_dwordx4 %4, %11, off sc0 sc1\n\t"
        "global_load_dwordx4 %5, %12, off sc0 sc1\n\t"
        "global_load_dwordx4 %6, %13, off sc0 sc1\n\t"
        "s_waitcnt vmcnt(0)"
        : "=&v"(v0), "=&v"(v1), "=&v"(v2), "=&v"(v3),
          "=&v"(v4), "=&v"(v5), "=&v"(v6)
        : "v"(p0), "v"(p1), "v"(p2), "v"(p3), "v"(p4), "v"(p5), "v"(p6)
        : "memory");
}

__device__ __forceinline__ void llc_store4(f32x4* p, f32x4 v) {
    asm volatile("global_store_dwordx4 %0, %1, off sc0 sc1"
                 :: "v"(p), "v"(v) : "memory");
}

__device__ __forceinline__ f32x4 vmin4(f32x4 a, f32x4 b) {
    f32x4 r;
    r[0] = fminf(a[0], b[0]); r[1] = fminf(a[1], b[1]);
    r[2] = fminf(a[2], b[2]); r[3] = fminf(a[3], b[3]);
    return r;
}

__global__ __launch_bounds__(256, 1) void fused_recur(
    const float* __restrict__ J,
    const float* __restrict__ net_in,     // [0,N): Iext ; [N,2N): r0
    float* __restrict__ out,              // U_13 (N) | recSum_13 (1) | r_13 (N)
    float* __restrict__ ws)               // 14 * 420 f32x4, sentinel-filled
{
    f32x4* bufs = (f32x4*)ws;

    const int tid  = threadIdx.x;
    const int lane = tid & 63;
    const int wave = tid >> 6;
    const int row0 = (int)blockIdx.x * RPB + wave * RPW;

    // ---- this wave's 4 J rows -> VGPRs (112 regs), read from HBM once ----
    f32x4 Jr[RPW][7];
    #pragma unroll
    for (int m = 0; m < RPW; ++m) {
        const f32x4* Jrow = (const f32x4*)(J + (size_t)(row0 + m) * N);
        #pragma unroll
        for (int k = 0; k < 7; ++k) {
            const int idx = lane + 64 * k;
            Jr[m][k] = (idx < NV4) ? Jrow[idx] : (f32x4)0.f;
        }
    }

    float iext[RPW];
    #pragma unroll
    for (int m = 0; m < RPW; ++m) iext[m] = net_in[row0 + m];

    float Uv[RPW], Qv[RPW];

    #pragma unroll 1
    for (int t = 0; t < NSTEP; ++t) {
        // Loop-carried register tie: J fragments cannot be rematerialized
        // from memory — they must stay resident in VGPRs across iterations.
        #pragma unroll
        for (int m = 0; m < RPW; ++m)
            #pragma unroll
            for (int k = 0; k < 7; ++k)
                asm volatile("" : "+v"(Jr[m][k]));

        f32x4 rv[7];
        float psum = 0.0f;

        if (t == 0) {
            const f32x4* r0 = (const f32x4*)(net_in + N);
            #pragma unroll
            for (int k = 0; k < 7; ++k) {
                const int idx = lane + 64 * k;
                rv[k] = (idx < NV4) ? r0[idx] : (f32x4)0.f;
            }
        } else {
            const f32x4* base = bufs + (size_t)(t - 1) * NV4;
            const f32x4* q0 = base + (lane);
            const f32x4* q1 = base + (lane + 64);
            const f32x4* q2 = base + (lane + 128);
            const f32x4* q3 = base + (lane + 192);
            const f32x4* q4 = base + (lane + 256);
            const f32x4* q5 = base + (lane + 320);
            const f32x4* q6 = (lane < 36) ? (base + lane + 384) : base; // OOB->quad0
            for (;;) {
                load7_llc(q0, q1, q2, q3, q4, q5, q6,
                          rv[0], rv[1], rv[2], rv[3], rv[4], rv[5], rv[6]);
                f32x4 m0 = vmin4(vmin4(rv[0], rv[1]), vmin4(rv[2], rv[3]));
                f32x4 m1 = vmin4(vmin4(rv[4], rv[5]), rv[6]);
                f32x4 mm = vmin4(m0, m1);
                const float mn = fminf(fminf(mm[0], mm[1]), fminf(mm[2], mm[3]));
                if (mn >= 0.0f) break;   // all 28 elems valid (sq >= 0)
            }
            if (lane >= 36) rv[6] = (f32x4)0.f;   // exclude quad-0 stand-in
            #pragma unroll
            for (int k = 0; k < 7; ++k)
                psum += (rv[k][0] + rv[k][1]) + (rv[k][2] + rv[k][3]);
        }

        // 4 row-dots + s-partial, one 5-value butterfly reduce
        float red[5];
        #pragma unroll
        for (int m = 0; m < RPW; ++m) {
            float acc = 0.f;
            #pragma unroll
            for (int k = 0; k < 7; ++k) {
                acc += Jr[m][k][0] * rv[k][0];
                acc += Jr[m][k][1] * rv[k][1];
                acc += Jr[m][k][2] * rv[k][2];
                acc += Jr[m][k][3] * rv[k][3];
            }
            red[m] = acc;
        }
        red[4] = psum;
        #pragma unroll
        for (int off = 32; off; off >>= 1) {
            #pragma unroll
            for (int i = 0; i < 5; ++i) red[i] += __shfl_xor(red[i], off, 64);
        }
        const float s = (t == 0) ? 1.0f : 0.005f * red[4];

        #pragma unroll
        for (int m = 0; m < RPW; ++m) {
            const float U  = red[m] / s + iext[m];      // ALPHA=BETA=1
            const float u2 = 0.2f * U;
            Uv[m] = U;
            Qv[m] = u2 * u2;                            // sq >= 0 always
        }

        // publish this wave's 4 rows: the store IS the signal
        if (lane == 0) {
            f32x4 pub = { Qv[0], Qv[1], Qv[2], Qv[3] };
            llc_store4(bufs + (size_t)t * NV4 + (row0 >> 2), pub);
        }
    }

    // ---- final: poll buf[13] for s13 (wave-local), write outputs ----
    float s13;
    {
        const f32x4* base = bufs + (size_t)(NSTEP - 1) * NV4;
        const f32x4* q0 = base + (lane);
        const f32x4* q1 = base + (lane + 64);
        const f32x4* q2 = base + (lane + 128);
        const f32x4* q3 = base + (lane + 192);
        const f32x4* q4 = base + (lane + 256);
        const f32x4* q5 = base + (lane + 320);
        const f32x4* q6 = (lane < 36) ? (base + lane + 384) : base;
        f32x4 rv[7];
        for (;;) {
            load7_llc(q0, q1, q2, q3, q4, q5, q6,
                      rv[0], rv[1], rv[2], rv[3], rv[4], rv[5], rv[6]);
            f32x4 m0 = vmin4(vmin4(rv[0], rv[1]), vmin4(rv[2], rv[3]));
            f32x4 m1 = vmin4(vmin4(rv[4], rv[5]), rv[6]);
            f32x4 mm = vmin4(m0, m1);
            const float mn = fminf(fminf(mm[0], mm[1]), fminf(mm[2], mm[3]));
            if (mn >= 0.0f) break;
        }
        if (lane >= 36) rv[6] = (f32x4)0.f;
        float psum = 0.f;
        #pragma unroll
        for (int k = 0; k < 7; ++k)
            psum += (rv[k][0] + rv[k][1]) + (rv[k][2] + rv[k][3]);
        #pragma unroll
        for (int off = 32; off; off >>= 1) psum += __shfl_xor(psum, off, 64);
        s13 = 0.005f * psum;
    }

    if (lane == 0) {
        f32x4 u4 = { Uv[0], Uv[1], Uv[2], Uv[3] };
        *(f32x4*)(out + row0) = u4;                     // U_13 (16B aligned)
    }
    if (lane < RPW) {                                   // r_13 (offset N+1: scalar)
        const float q = (lane == 0) ? Qv[0] : (lane == 1) ? Qv[1]
                       : (lane == 2) ? Qv[2] : Qv[3];
        out[N + 1 + row0 + lane] = q / s13;
    }
    if (blockIdx.x == 0 && tid == 0) out[N] = s13;      // recSum_13
}

extern "C" void kernel_launch(void* const* d_in, const int* in_sizes, int n_in,
                              void* d_out, int out_size, void* d_ws, size_t ws_size,
                              hipStream_t stream) {
    const float* net_in = (const float*)d_in[0];   // 2N: Iext | r0
    const float* J      = (const float*)d_in[1];   // N x N row-major
    // Sentinel-fill all 14 step buffers: every byte 0xBF -> -1.498f (< 0).
    hipMemsetAsync(d_ws, 0xBF, (size_t)NSTEP * NV4 * sizeof(f32x4), stream);
    fused_recur<<<GBLK, 256, 0, stream>>>(J, net_in, (float*)d_out, (float*)d_ws);
}

// Round 5
// 108.303 us; speedup vs baseline: 1.0813x; 1.0813x over previous
//
#include <hip/hip_runtime.h>

// Fused persistent kernel — wave-local steps, hierarchical detect.
// 14-step recurrence, N=1680:
//   temp = J @ r_{t-1};  U = temp + Iext;  sq = (0.2U)^2
//   recSum = 0.005*sum(sq);  r_t = sq/recSum
// Invariant: carry unnormalized r̃_t = sq_t;  s_t = 0.005*sum(r̃_t);
//   J @ r_{t-1} = (J @ r̃_{t-1}) / s_{t-1}.
//
// Protocol (data IS the barrier): 14 per-step buffers of 420 quads,
// sentinel-filled 0xBF (-1.498f < 0) per launch; a quad is valid iff all
// elems >= 0 (sq is a square; every element is checked -> tear-safe).
// Round-5 change: only WAVE 0 of each block runs the poll loop (105
// pollers, not 420 -> 4x less poll traffic contending with the publish
// stores). On detect it release-stores an LDS flag; waves 1-3 spin on
// the flag (local, free) and then bulk-load the known-valid data ONCE.
// No __syncthreads in the loop, no fences, publish = one sc0|sc1 store.

typedef float f32x4 __attribute__((ext_vector_type(4)));

#define N      1680
#define NV4    420          // N/4
#define NSTEP  14
#define GBLK   105          // blocks; 105*16 = 1680 rows
#define RPB    16           // rows per block
#define RPW    4            // rows per wave

__device__ __forceinline__ void load7_llc(
    const f32x4* p0, const f32x4* p1, const f32x4* p2, const f32x4* p3,
    const f32x4* p4, const f32x4* p5, const f32x4* p6,
    f32x4& v0, f32x4& v1, f32x4& v2, f32x4& v3,
    f32x4& v4, f32x4& v5, f32x4& v6)
{
    asm volatile(
        "global_load_dwordx4 %0, %7, off sc0 sc1\n\t"
        "global_load_dwordx4 %1, %8, off sc0 sc1\n\t"
        "global_load_dwordx4 %2, %9, off sc0 sc1\n\t"
        "global_load_dwordx4 %3, %10, off sc0 sc1\n\t"
        "global_load_dwordx4 %4, %11, off sc0 sc1\n\t"
        "global_load_dwordx4 %5, %12, off sc0 sc1\n\t"
        "global_load_dwordx4 %6, %13, off sc0 sc1\n\t"
        "s_waitcnt vmcnt(0)"
        : "=&v"(v0), "=&v"(v1), "=&v"(v2), "=&v"(v3),
          "=&v"(v4), "=&v"(v5), "=&v"(v6)
        : "v"(p0), "v"(p1), "v"(p2), "v"(p3), "v"(p4), "v"(p5), "v"(p6)
        : "memory");
}

__device__ __forceinline__ void llc_store4(f32x4* p, f32x4 v) {
    asm volatile("global_store_dwordx4 %0, %1, off sc0 sc1"
                 :: "v"(p), "v"(v) : "memory");
}

__device__ __forceinline__ f32x4 vmin4(f32x4 a, f32x4 b) {
    f32x4 r;
    r[0] = fminf(a[0], b[0]); r[1] = fminf(a[1], b[1]);
    r[2] = fminf(a[2], b[2]); r[3] = fminf(a[3], b[3]);
    return r;
}

__global__ __launch_bounds__(256, 1) void fused_recur(
    const float* __restrict__ J,
    const float* __restrict__ net_in,     // [0,N): Iext ; [N,2N): r0
    float* __restrict__ out,              // U_13 (N) | recSum_13 (1) | r_13 (N)
    float* __restrict__ ws)               // 14 * 420 f32x4, sentinel-filled
{
    __shared__ int step_flag[NSTEP];      // set by wave 0 on detect of buf[t]

    f32x4* bufs = (f32x4*)ws;

    const int tid  = threadIdx.x;
    const int lane = tid & 63;
    const int wave = tid >> 6;
    const int row0 = (int)blockIdx.x * RPB + wave * RPW;

    if (tid < NSTEP) step_flag[tid] = 0;
    __syncthreads();                      // one-time flag init (only barrier)

    // ---- this wave's 4 J rows -> VGPRs, read once; one-time opaque tie ----
    f32x4 Jr[RPW][7];
    #pragma unroll
    for (int m = 0; m < RPW; ++m) {
        const f32x4* Jrow = (const f32x4*)(J + (size_t)(row0 + m) * N);
        #pragma unroll
        for (int k = 0; k < 7; ++k) {
            const int idx = lane + 64 * k;
            Jr[m][k] = (idx < NV4) ? Jrow[idx] : (f32x4)0.f;
        }
    }
    #pragma unroll
    for (int m = 0; m < RPW; ++m)
        #pragma unroll
        for (int k = 0; k < 7; ++k)
            asm volatile("" : "+v"(Jr[m][k]));

    float iext[RPW];
    #pragma unroll
    for (int m = 0; m < RPW; ++m) iext[m] = net_in[row0 + m];

    float Uv[RPW], Qv[RPW];

    #pragma unroll 1
    for (int t = 0; t <= NSTEP; ++t) {    // t==NSTEP: finish pass (s13 only)
        f32x4 rv[7];
        float psum = 0.0f;

        if (t == 0) {
            const f32x4* r0 = (const f32x4*)(net_in + N);
            #pragma unroll
            for (int k = 0; k < 7; ++k) {
                const int idx = lane + 64 * k;
                rv[k] = (idx < NV4) ? r0[idx] : (f32x4)0.f;
            }
        } else {
            const f32x4* base = bufs + (size_t)(t - 1) * NV4;
            const f32x4* q0 = base + (lane);
            const f32x4* q1 = base + (lane + 64);
            const f32x4* q2 = base + (lane + 128);
            const f32x4* q3 = base + (lane + 192);
            const f32x4* q4 = base + (lane + 256);
            const f32x4* q5 = base + (lane + 320);
            const f32x4* q6 = (lane < 36) ? (base + lane + 384) : base; // OOB->quad0

            if (wave == 0) {
                // sole poller: checks EVERY element of EVERY quad (tear-safe)
                for (;;) {
                    load7_llc(q0, q1, q2, q3, q4, q5, q6,
                              rv[0], rv[1], rv[2], rv[3], rv[4], rv[5], rv[6]);
                    f32x4 m0 = vmin4(vmin4(rv[0], rv[1]), vmin4(rv[2], rv[3]));
                    f32x4 m1 = vmin4(vmin4(rv[4], rv[5]), rv[6]);
                    f32x4 mm = vmin4(m0, m1);
                    const float mn = fminf(fminf(mm[0], mm[1]),
                                           fminf(mm[2], mm[3]));
                    if (mn >= 0.0f) break;
                }
                if (lane == 0)
                    __hip_atomic_store(&step_flag[t - 1], 1, __ATOMIC_RELEASE,
                                       __HIP_MEMORY_SCOPE_WORKGROUP);
            } else {
                // spin on the local flag (no memory-system traffic), then
                // bulk-load the known-valid data exactly once
                while (__hip_atomic_load(&step_flag[t - 1], __ATOMIC_ACQUIRE,
                                         __HIP_MEMORY_SCOPE_WORKGROUP) == 0) {}
                load7_llc(q0, q1, q2, q3, q4, q5, q6,
                          rv[0], rv[1], rv[2], rv[3], rv[4], rv[5], rv[6]);
            }
            if (lane >= 36) rv[6] = (f32x4)0.f;   // exclude quad-0 stand-in
            #pragma unroll
            for (int k = 0; k < 7; ++k)
                psum += (rv[k][0] + rv[k][1]) + (rv[k][2] + rv[k][3]);
        }

        if (t == NSTEP) {                 // finish: only s13 needed
            #pragma unroll
            for (int off = 32; off; off >>= 1) psum += __shfl_xor(psum, off, 64);
            const float s13 = 0.005f * psum;

            if (lane == 0) {
                f32x4 u4 = { Uv[0], Uv[1], Uv[2], Uv[3] };
                *(f32x4*)(out + row0) = u4;                 // U_13
            }
            if (lane < RPW) {                               // r_13
                const float q = (lane == 0) ? Qv[0] : (lane == 1) ? Qv[1]
                               : (lane == 2) ? Qv[2] : Qv[3];
                out[N + 1 + row0 + lane] = q / s13;
            }
            if (blockIdx.x == 0 && tid == 0) out[N] = s13;  // recSum_13
            break;
        }

        // 4 row-dots + s-partial, one 5-value butterfly reduce
        float red[5];
        #pragma unroll
        for (int m = 0; m < RPW; ++m) {
            float acc = 0.f;
            #pragma unroll
            for (int k = 0; k < 7; ++k) {
                acc += Jr[m][k][0] * rv[k][0];
                acc += Jr[m][k][1] * rv[k][1];
                acc += Jr[m][k][2] * rv[k][2];
                acc += Jr[m][k][3] * rv[k][3];
            }
            red[m] = acc;
        }
        red[4] = psum;
        #pragma unroll
        for (int off = 32; off; off >>= 1) {
            #pragma unroll
            for (int i = 0; i < 5; ++i) red[i] += __shfl_xor(red[i], off, 64);
        }
        const float s = (t == 0) ? 1.0f : 0.005f * red[4];

        #pragma unroll
        for (int m = 0; m < RPW; ++m) {
            const float U  = red[m] / s + iext[m];      // ALPHA=BETA=1
            const float u2 = 0.2f * U;
            Uv[m] = U;
            Qv[m] = u2 * u2;                            // sq >= 0 always
        }

        // publish this wave's 4 rows: the store IS the signal
        if (lane == 0) {
            f32x4 pub = { Qv[0], Qv[1], Qv[2], Qv[3] };
            llc_store4(bufs + (size_t)t * NV4 + (row0 >> 2), pub);
        }
    }
}

extern "C" void kernel_launch(void* const* d_in, const int* in_sizes, int n_in,
                              void* d_out, int out_size, void* d_ws, size_t ws_size,
                              hipStream_t stream) {
    const float* net_in = (const float*)d_in[0];   // 2N: Iext | r0
    const float* J      = (const float*)d_in[1];   // N x N row-major
    // Sentinel-fill all 14 step buffers: every byte 0xBF -> -1.498f (< 0).
    hipMemsetAsync(d_ws, 0xBF, (size_t)NSTEP * NV4 * sizeof(f32x4), stream);
    fused_recur<<<GBLK, 256, 0, stream>>>(J, net_in, (float*)d_out, (float*)d_ws);
}